// Round 10
// baseline (464.808 us; speedup 1.0000x reference)
//
#include <hip/hip_runtime.h>
#include <cmath>

// Problem constants (from reference)
#define NN  5      // N_NODES
#define BB  4      // batch
#define CCH 256    // channels
#define HWD 1024   // H*W
#define THRESH_V 0.3f
#define EPS_V 1e-12f

// R10: barrier-free streaming GEMM. Ten rounds of data show every barriered
// LDS-staged variant pins at wall ~= 1.8x VALU-busy (R8 best: 290us), with an
// LDS-pipe floor (~165us) above the FMA floor (102us). This round removes the
// LDS pipe AND the barriers from the main loop entirely:
//   - wave tile 64x32, acc[8][4] = 32 VGPRs (no spill-cliff exposure)
//   - A (=W1+W2 / W2) read per-kk from the ws-transposed table: 2 dwordx4,
//     8x lane-broadcast, L1/L2-resident (table = 2.6MB, XCD-clustered)
//   - X read per-kk: 1 dwordx4, 128B/wave, L2-resident, 20 blocks share
//   - rolling pointers, depth-1 rotation, no __syncthreads until epilogue
// A vmcnt-stalled wave never blocks others; ~6 waves/SIMD of TLP fill VALU.
// LDS (13.8KB) is used only by the fused epilogue exchange.

#define CT 64      // channel rows per block
#define WT 32      // hw cols per block
#define SPAD 36    // Es row stride (floats) in epilogue

#define W2T_OFF (NN * CCH * CCH)          // second table in ws
#define SMEM_FLOATS (6 * 16 * SPAD)       // 3456 floats = 13824 B

// ---------------- prep: transpose conv_w into ws (verified R3) ----------------
// ws: At[i][k][c] = W1[i][c][k] + W2[i][c][k];  W2t[i][k][c] = W2[i][c][k]
__global__ void fub_prep(const float* __restrict__ conv_w, float* __restrict__ ws)
{
    const int t = blockIdx.x * 256 + threadIdx.x;   // 0 .. 5*256*64-1
    if (t >= NN * CCH * 64) return;
    const int c4 = (t & 63) << 2;        // c base 0..252
    const int k  = (t >> 6) & 255;       // 0..255
    const int i  = t >> 14;              // 0..4
    float s1[4], s2[4];
#pragma unroll
    for (int cc = 0; cc < 4; ++cc) {
        const float* p = conv_w + (size_t)(i * CCH + c4 + cc) * (2 * CCH) + k;
        const float w1 = p[0];
        const float w2 = p[CCH];
        s1[cc] = w1 + w2;
        s2[cc] = w2;
    }
    float* At  = ws + (size_t)(i * CCH + k) * CCH + c4;
    float* W2t = ws + W2T_OFF + (size_t)(i * CCH + k) * CCH + c4;
    *(float4*)At  = make_float4(s1[0], s1[1], s1[2], s1[3]);
    *(float4*)W2t = make_float4(s2[0], s2[1], s2[2], s2[3]);
}

// ---------------- main ----------------
__global__ __launch_bounds__(384, 3)
void fub_main(const float* __restrict__ x, const float* __restrict__ wmat,
              const float* __restrict__ ws, const float* __restrict__ conv_b,
              float* __restrict__ out)
{
    __shared__ __align__(16) float Es[SMEM_FLOATS];   // [6][16][SPAD]

    const int tid  = threadIdx.x;
    const int wv   = tid >> 6;        // 0..5 : stream id
    const int lane = tid & 63;

    // XCD-chunked bijective swizzle (2560 % 8 == 0): the 20 blocks sharing one
    // x panel (b,hwt) land on one XCD's L2; A tables shared across all.
    const int wg  = blockIdx.x;
    int L = (wg & 7) * 320 + (wg >> 3);
    const int i   = L % 5;  L /= 5;
    const int ct  = L & 3;  L >>= 2;
    const int b   = L & 3;  L >>= 2;
    const int hwt = L;                 // 0..31

    const int c0  = ct * CT;
    const int hw0 = hwt * WT;

    const int lr = (lane >> 3) << 3;  // row base 0,8,...,56 (8 rows/lane)
    const int lc = (lane & 7)  << 2;  // col base 0,4,...,28 (4 cols/lane)

    // stream w<5: A_i @ x[w]; stream 5: W2_i @ x[i]
    const int jx = (wv < NN) ? wv : i;
    const float* Ap = ws + (size_t)((wv == NN) ? W2T_OFF : 0)
                         + (size_t)i * CCH * CCH + c0 + lr;     // +CCH per kk
    const float* Xp = x + (size_t)((jx * BB + b) * CCH) * HWD + hw0 + lc; // +HWD per kk

    float acc[8][4];
#pragma unroll
    for (int r = 0; r < 8; ++r)
#pragma unroll
        for (int c = 0; c < 4; ++c) acc[r][c] = 0.0f;

    float4 a0 = *(const float4*)Ap;
    float4 a1 = *(const float4*)(Ap + 4);
    float4 xv = *(const float4*)Xp;

#pragma unroll 4
    for (int k = 0; k < 255; ++k) {
        const float* An = Ap + CCH;
        const float* Xn = Xp + HWD;
        const float4 na0 = *(const float4*)An;
        const float4 na1 = *(const float4*)(An + 4);
        const float4 nx  = *(const float4*)Xn;

        const float ar[8] = {a0.x, a0.y, a0.z, a0.w, a1.x, a1.y, a1.z, a1.w};
        const float xc[4] = {xv.x, xv.y, xv.z, xv.w};
#pragma unroll
        for (int r = 0; r < 8; ++r)
#pragma unroll
            for (int c = 0; c < 4; ++c)
                acc[r][c] = fmaf(ar[r], xc[c], acc[r][c]);

        a0 = na0; a1 = na1; xv = nx;
        Ap = An; Xp = Xn;
    }
    {   // k = 255, no further prefetch
        const float ar[8] = {a0.x, a0.y, a0.z, a0.w, a1.x, a1.y, a1.z, a1.w};
        const float xc[4] = {xv.x, xv.y, xv.z, xv.w};
#pragma unroll
        for (int r = 0; r < 8; ++r)
#pragma unroll
            for (int c = 0; c < 4; ++c)
                acc[r][c] = fmaf(ar[r], xc[c], acc[r][c]);
    }

    // ---- epilogue: 4 passes over 16-row bands; exchange streams via LDS ----
    const int rhme  = lr >> 4;        // band of this lane's rows (0..3)
    const int rbase = lr & 15;        // 0 or 8

    float wrow[NN];
#pragma unroll
    for (int j = 0; j < NN; ++j) wrow[j] = wmat[i * NN + j];

#pragma unroll
    for (int rh = 0; rh < 4; ++rh) {
        if (rhme == rh) {
            float* Eb = Es + wv * (16 * SPAD) + lc;
#pragma unroll
            for (int r = 0; r < 8; ++r)
                *(float4*)(Eb + (rbase + r) * SPAD) =
                    make_float4(acc[r][0], acc[r][1], acc[r][2], acc[r][3]);
        }
        __syncthreads();

        if (tid < 256) {
            const int row  = tid >> 4;           // 0..15
            const int col2 = (tid & 15) << 1;    // 0..30 step 2
            const int c    = c0 + rh * 16 + row;
            const float bias = conv_b[i * CCH + c];

            const float2 T = *(const float2*)(Es + 5 * (16 * SPAD) + row * SPAD + col2);
            const float Tv[2] = {T.x, T.y};

            float num[2] = {0.f, 0.f};
            float sq [2] = {0.f, 0.f};
#pragma unroll
            for (int j = 0; j < NN; ++j) {
                const float2 s  = *(const float2*)(Es + j * (16 * SPAD) + row * SPAD + col2);
                const float2 xj = *(const float2*)(
                    x + (size_t)((j * BB + b) * CCH + c) * HWD + hw0 + col2);
                const float sv[2] = {s.x, s.y};
                const float xvv[2] = {xj.x, xj.y};
#pragma unroll
                for (int cc = 0; cc < 2; ++cc) {
                    const float target = sv[cc] + Tv[cc] + bias;
                    const float dist   = xvv[cc] - target;
                    const float z      = dist * wrow[j];
                    float e = 1.0f / (1.0f + expf(-z));
                    e = (e > THRESH_V) ? e : 0.0f;
                    sq[cc]  = fmaf(e, e, sq[cc]);
                    num[cc] = fmaf(e, xvv[cc], num[cc]);
                }
            }
            float2 res;
            res.x = num[0] / fmaxf(sqrtf(sq[0]), EPS_V);
            res.y = num[1] / fmaxf(sqrtf(sq[1]), EPS_V);
            *(float2*)(out + (size_t)((i * BB + b) * CCH + c) * HWD + hw0 + col2) = res;
        }
        __syncthreads();
    }
}

extern "C" void kernel_launch(void* const* d_in, const int* in_sizes, int n_in,
                              void* d_out, int out_size, void* d_ws, size_t ws_size,
                              hipStream_t stream) {
    const float* x      = (const float*)d_in[0];
    const float* w      = (const float*)d_in[1];
    const float* conv_w = (const float*)d_in[2];
    const float* conv_b = (const float*)d_in[3];
    float* out = (float*)d_out;
    float* ws  = (float*)d_ws;   // needs 2*5*256*256*4 B = 2.62 MB

    // prep: 5*256*64 = 81920 work items
    fub_prep<<<dim3(320), dim3(256), 0, stream>>>(conv_w, ws);

    // grid: hwt(32) * b(4) * ct(4) * i(5) = 2560 blocks of 384 threads
    fub_main<<<dim3(2560), dim3(384), 0, stream>>>(x, w, ws, conv_b, out);
}

// Round 11
// 358.716 us; speedup vs baseline: 1.2958x; 1.2958x over previous
//
#include <hip/hip_runtime.h>
#include <cmath>

// Problem constants (from reference)
#define NN  5      // N_NODES
#define BB  4      // batch
#define CCH 256    // channels
#define HWD 1024   // H*W
#define THRESH_V 0.3f
#define EPS_V 1e-12f

// R11 = R8 (all-LDS 64x64 tile, KC=16, ws-pretransposed A) + two coupled fixes:
//  1) amdgpu_waves_per_eu(2,3): pins the backend's occupancy-chasing (R5/R7/
//     R10 all lost registers to it: 64/84/48 VGPR -> spill or serialization).
//     Budget ~170 VGPR, 2 blocks/CU.
//  2) double-buffered LDS staging, ONE barrier per chunk: issue chunk t+1
//     global loads -> regs BEFORE compute(t), ds_write after, then sync.
//     Kills the stage/compute barrier alternation that pinned every variant
//     at wall ~= 1.8x VALU-busy.
// Staging rows are unpadded [16][64]: A/X LDS reads are 8-distinct-address
// broadcasts (offsets 0,32,...,224B = all 32 banks once) -> conflict-free.

#define CT 64      // channel rows per block
#define WT 64      // hw cols per block
#define KC 16      // k chunk
#define SPAD 68    // Es row stride (floats) in epilogue

#define W2T_OFF (NN * CCH * CCH)     // second table in ws

// LDS: per buffer Xs[5][16][64] (5120) | As[16][64] @5120 | W2s[16][64] @6144
#define BUFSZ   7168
#define AS_OFF  5120
#define W2S_OFF 6144
#define SMEM_FLOATS (2 * BUFSZ)      // 14336 floats = 57344 B
// epilogue overlay Es[6][16][SPAD] = 6528 floats (fits in buffer 0)

// ---------------- prep: transpose conv_w into ws (verified R3) ----------------
// ws: At[i][k][c] = W1[i][c][k] + W2[i][c][k];  W2t[i][k][c] = W2[i][c][k]
__global__ void fub_prep(const float* __restrict__ conv_w, float* __restrict__ ws)
{
    const int t = blockIdx.x * 256 + threadIdx.x;   // 0 .. 5*256*64-1
    if (t >= NN * CCH * 64) return;
    const int c4 = (t & 63) << 2;        // c base 0..252
    const int k  = (t >> 6) & 255;       // 0..255
    const int i  = t >> 14;              // 0..4
    float s1[4], s2[4];
#pragma unroll
    for (int cc = 0; cc < 4; ++cc) {
        const float* p = conv_w + (size_t)(i * CCH + c4 + cc) * (2 * CCH) + k;
        const float w1 = p[0];
        const float w2 = p[CCH];
        s1[cc] = w1 + w2;
        s2[cc] = w2;
    }
    float* At  = ws + (size_t)(i * CCH + k) * CCH + c4;
    float* W2t = ws + W2T_OFF + (size_t)(i * CCH + k) * CCH + c4;
    *(float4*)At  = make_float4(s1[0], s1[1], s1[2], s1[3]);
    *(float4*)W2t = make_float4(s2[0], s2[1], s2[2], s2[3]);
}

// ---------------- main ----------------
__global__ __launch_bounds__(384) __attribute__((amdgpu_waves_per_eu(2, 3)))
void fub_main(const float* __restrict__ x, const float* __restrict__ wmat,
              const float* __restrict__ ws, const float* __restrict__ conv_b,
              float* __restrict__ out)
{
    __shared__ __align__(16) float smem[SMEM_FLOATS];
    float* Es = smem;                  // [6][16][SPAD] overlay (epilogue only)

    const int tid  = threadIdx.x;
    const int wv   = tid >> 6;        // 0..5 : stream id
    const int lane = tid & 63;

    // XCD-chunked bijective swizzle (1280 % 8 == 0)
    const int wg  = blockIdx.x;
    int L = (wg & 7) * 160 + (wg >> 3);
    const int i   = L % 5;  L /= 5;
    const int ct  = L & 3;  L >>= 2;
    const int b   = L & 3;  L >>= 2;
    const int hwt = L;                 // 0..15

    const int c0  = ct * CT;
    const int hw0 = hwt * WT;

    const int lr = (lane >> 3) << 3;  // frag row base 0,8,...,56
    const int lc = (lane & 7)  << 3;  // frag col base 0,8,...,56

    // stream w<5: A_i @ x[w]; stream 5: W2_i @ x[i]
    const int jx    = (wv < NN) ? wv : i;
    const int msoff = (wv == 5) ? W2S_OFF : AS_OFF;
    const float* Mb = smem + msoff + lr;
    const float* Xb = smem + jx * (KC * WT) + lc;

    // ---- staging roles: waves 0-3 stage X (5 float4), waves 4-5 stage A/W2 (4) ----
    const bool xrole = (tid < 256);
    const float *p0, *p1, *p2, *p3, *p4;
    int l0, l1, l2, l3, l4;
    if (xrole) {
#define XSET(IT, P, LV) { const int idx = tid + IT * 256;               \
        const int j = idx >> 8, rem = idx & 255;                        \
        const int kk = rem >> 4, q4 = (rem & 15) << 2;                  \
        P  = x + (size_t)((j * BB + b) * CCH + kk) * HWD + hw0 + q4;    \
        LV = j * (KC * WT) + kk * 64 + q4; }
        XSET(0, p0, l0) XSET(1, p1, l1) XSET(2, p2, l2) XSET(3, p3, l3) XSET(4, p4, l4)
#undef XSET
    } else {
        const int u = tid - 256;
#define ASET(IT, P, LV) { const int idx = u + IT * 128;                 \
        const int tbl = idx >> 8, rem = idx & 255;                      \
        const int kk = rem >> 4, c4 = (rem & 15) << 2;                  \
        P  = ws + (size_t)(tbl ? W2T_OFF : 0)                           \
               + (size_t)(i * CCH + kk) * CCH + c0 + c4;                \
        LV = (tbl ? W2S_OFF : AS_OFF) + kk * 64 + c4; }
        ASET(0, p0, l0) ASET(1, p1, l1) ASET(2, p2, l2) ASET(3, p3, l3)
#undef ASET
        p4 = p3; l4 = l3;              // unused in A-role
    }

    float4 s0, s1, s2, s3, s4;

#define STAGE_LOAD() do {                                               \
        s0 = *(const float4*)p0; s1 = *(const float4*)p1;               \
        s2 = *(const float4*)p2; s3 = *(const float4*)p3;               \
        if (xrole) {                                                    \
            s4 = *(const float4*)p4;                                    \
            p0 += KC * HWD; p1 += KC * HWD; p2 += KC * HWD;             \
            p3 += KC * HWD; p4 += KC * HWD;                             \
        } else {                                                        \
            p0 += KC * CCH; p1 += KC * CCH;                             \
            p2 += KC * CCH; p3 += KC * CCH;                             \
        }                                                               \
    } while (0)

#define STAGE_WRITE(BO) do {                                            \
        *(float4*)(smem + (BO) + l0) = s0;                              \
        *(float4*)(smem + (BO) + l1) = s1;                              \
        *(float4*)(smem + (BO) + l2) = s2;                              \
        *(float4*)(smem + (BO) + l3) = s3;                              \
        if (xrole) *(float4*)(smem + (BO) + l4) = s4;                   \
    } while (0)

    float acc[8][8];
#pragma unroll
    for (int r = 0; r < 8; ++r)
#pragma unroll
        for (int c = 0; c < 8; ++c) acc[r][c] = 0.0f;

#define COMPUTE(BO) do {                                                \
        _Pragma("unroll 4")                                             \
        for (int kk = 0; kk < KC; ++kk) {                               \
            const float4 a0 = *(const float4*)(Mb + (BO) + kk * 64);    \
            const float4 a1 = *(const float4*)(Mb + (BO) + kk * 64 + 4);\
            const float4 x0 = *(const float4*)(Xb + (BO) + kk * 64);    \
            const float4 x1 = *(const float4*)(Xb + (BO) + kk * 64 + 4);\
            const float ar[8] = {a0.x,a0.y,a0.z,a0.w,a1.x,a1.y,a1.z,a1.w}; \
            const float xc[8] = {x0.x,x0.y,x0.z,x0.w,x1.x,x1.y,x1.z,x1.w}; \
            _Pragma("unroll")                                           \
            for (int r = 0; r < 8; ++r)                                 \
                _Pragma("unroll")                                       \
                for (int c = 0; c < 8; ++c)                             \
                    acc[r][c] = fmaf(ar[r], xc[c], acc[r][c]);          \
        }                                                               \
    } while (0)

    // prologue: chunk 0 -> buffer 0
    STAGE_LOAD();
    STAGE_WRITE(0);
    __syncthreads();

    // 8 x 2-phase: compute chunk 2t (buf0) / 2t+1 (buf1); prefetch next ahead
#pragma unroll 1
    for (int t = 0; t < 8; ++t) {
        STAGE_LOAD();                  // chunk 2t+1 -> regs (in flight)
        COMPUTE(0);                    // chunk 2t
        STAGE_WRITE(BUFSZ);            // vmcnt drains here, after compute
        __syncthreads();
        if (t < 7) STAGE_LOAD();       // chunk 2t+2 -> regs
        COMPUTE(BUFSZ);                // chunk 2t+1
        if (t < 7) STAGE_WRITE(0);
        __syncthreads();
    }

    // ---- epilogue: 4 passes over 16-row bands; exchange streams via LDS ----
    const int rhme  = lr >> 4;        // which 16-row band this lane's frag is in
    const int rbase = lr & 15;        // 0 or 8

    float wrow[NN];
#pragma unroll
    for (int j = 0; j < NN; ++j) wrow[j] = wmat[i * NN + j];

#pragma unroll
    for (int rh = 0; rh < 4; ++rh) {
        if (rhme == rh) {
            float* Eb = Es + wv * (16 * SPAD) + lc;
#pragma unroll
            for (int r = 0; r < 8; ++r) {
                *(float4*)(Eb + (rbase + r) * SPAD) =
                    make_float4(acc[r][0], acc[r][1], acc[r][2], acc[r][3]);
                *(float4*)(Eb + (rbase + r) * SPAD + 4) =
                    make_float4(acc[r][4], acc[r][5], acc[r][6], acc[r][7]);
            }
        }
        __syncthreads();

        if (tid < 256) {
            const int row  = tid >> 4;           // 0..15
            const int colq = (tid & 15) << 2;    // 0..60
            const int c    = c0 + rh * 16 + row;
            const float bias = conv_b[i * CCH + c];

            const float4 T = *(const float4*)(Es + 5 * (16 * SPAD) + row * SPAD + colq);
            const float Tv[4] = {T.x, T.y, T.z, T.w};

            float num[4] = {0.f, 0.f, 0.f, 0.f};
            float sq [4] = {0.f, 0.f, 0.f, 0.f};
#pragma unroll
            for (int j = 0; j < NN; ++j) {
                const float4 s  = *(const float4*)(Es + j * (16 * SPAD) + row * SPAD + colq);
                const float4 xj = *(const float4*)(
                    x + (size_t)((j * BB + b) * CCH + c) * HWD + hw0 + colq);
                const float sv[4] = {s.x, s.y, s.z, s.w};
                const float xv[4] = {xj.x, xj.y, xj.z, xj.w};
#pragma unroll
                for (int cc = 0; cc < 4; ++cc) {
                    const float target = sv[cc] + Tv[cc] + bias;
                    const float dist   = xv[cc] - target;
                    const float z      = dist * wrow[j];
                    float e = 1.0f / (1.0f + expf(-z));
                    e = (e > THRESH_V) ? e : 0.0f;
                    sq[cc]  = fmaf(e, e, sq[cc]);
                    num[cc] = fmaf(e, xv[cc], num[cc]);
                }
            }
            float4 res;
            res.x = num[0] / fmaxf(sqrtf(sq[0]), EPS_V);
            res.y = num[1] / fmaxf(sqrtf(sq[1]), EPS_V);
            res.z = num[2] / fmaxf(sqrtf(sq[2]), EPS_V);
            res.w = num[3] / fmaxf(sqrtf(sq[3]), EPS_V);
            *(float4*)(out + (size_t)((i * BB + b) * CCH + c) * HWD + hw0 + colq) = res;
        }
        __syncthreads();
    }
}

extern "C" void kernel_launch(void* const* d_in, const int* in_sizes, int n_in,
                              void* d_out, int out_size, void* d_ws, size_t ws_size,
                              hipStream_t stream) {
    const float* x      = (const float*)d_in[0];
    const float* w      = (const float*)d_in[1];
    const float* conv_w = (const float*)d_in[2];
    const float* conv_b = (const float*)d_in[3];
    float* out = (float*)d_out;
    float* ws  = (float*)d_ws;   // needs 2*5*256*256*4 B = 2.62 MB

    // prep: 5*256*64 = 81920 work items
    fub_prep<<<dim3(320), dim3(256), 0, stream>>>(conv_w, ws);

    // grid: hwt(16) * b(4) * ct(4) * i(5) = 1280 blocks of 384 threads
    fub_main<<<dim3(1280), dim3(384), 0, stream>>>(x, w, ws, conv_b, out);
}